// Round 15
// baseline (375.472 us; speedup 1.0000x reference)
//
#include <hip/hip_runtime.h>

// LocalFeatureAggregation — round 18: r17 nt-hint experiment, compile-fixed.
//  * r17 failed to COMPILE: __builtin_nontemporal_load rejects HIP_vector_type
//    structs (uint2/int4/float2). Fix: ext_vector_type typedefs (u32x2/i32x4/
//    f32x2) for the nt accesses — same codegen (global_load_dwordx2/x4 nt).
//  * Theory unchanged (r16 base = 205us main): WB frag table (32KB == L1) is
//    re-read every tile but evicted by zero-reuse streams (gathers/raw/nidx/
//    center/out). nt = evict-first HINT on those streams keeps WB L1-resident.
//  * Gates: VGPR <=128; WRITE ~65.5MB; FETCH ~147MB (jump >20% => revert
//    gather-half next round). Null => structural plateau.
// Requires ws_size >= 16864256 for the fast path (>= 86784 for fallback).

#define KNB   16
#define CR    10
#define CIN   64
#define CCAT  128
#define COUT  128
#define NPTS  131072
#define EPS   1e-5f
#define LOG2E 1.4426950408889634f

// d_ws layout (bytes)
#define WS_WB   0        // W_attn B-frags (pre-scaled by log2e): 2048 * 16 B = 32768
#define WS_W3   32768    // [W_out;W_sc] BN-folded B-frags: 3072 * 16 B = 49152
#define WS_WNB  81920    // W_nb BN-folded B-frags (K padded to 32): 256 * 16 B = 4096
#define WS_B3   86016    // bias3[128] fp32
#define WS_BNB  86528    // binb[64] fp32   -> 86784
#define WS_FEA  87040    // bf16 feature table [NPTS][CIN]: 16777216 B -> total 16864256

typedef const float* fp;
typedef short bf16x8 __attribute__((ext_vector_type(8)));
typedef float f32x4  __attribute__((ext_vector_type(4)));
typedef __bf16 bf16x2 __attribute__((ext_vector_type(2)));
// clang-native vector types for nontemporal builtins (HIP_vector_type rejected)
typedef unsigned int u32x2 __attribute__((ext_vector_type(2)));
typedef int          i32x4 __attribute__((ext_vector_type(4)));
typedef float        f32x2 __attribute__((ext_vector_type(2)));

__device__ __forceinline__ unsigned short f2bf(float x) {
    return __builtin_bit_cast(unsigned short, (__bf16)x);     // HW RNE cvt
}
__device__ __forceinline__ unsigned int pack2(float a, float b) {
    bf16x2 v; v.x = (__bf16)a; v.y = (__bf16)b;               // v_cvt_pk_bf16_f32
    return __builtin_bit_cast(unsigned int, v);
}
__device__ __forceinline__ float bf2f(unsigned short h) {
    return __uint_as_float(((unsigned int)h) << 16);
}
__device__ __forceinline__ float lrelu(float x) { return fmaxf(x, 0.2f * x); }

__device__ __forceinline__ u32x2 nt_u2(const void* p) {
    return __builtin_nontemporal_load((const u32x2*)p);
}
__device__ __forceinline__ i32x4 nt_i4(const void* p) {
    return __builtin_nontemporal_load((const i32x4*)p);
}
__device__ __forceinline__ f32x2 nt_f2(const void* p) {
    return __builtin_nontemporal_load((const f32x2*)p);
}
__device__ __forceinline__ void nt_stf(float* p, float v) {
    __builtin_nontemporal_store(v, p);
}

// ---------------------------------------------------------------------------
// Prep: build all weight-fragment tables in d_ws.
// ---------------------------------------------------------------------------
__global__ __launch_bounds__(256) void lfa_prep(
    fp W_nb, fp b_nb, fp g_nb, fp be_nb, fp m_nb, fp v_nb,
    fp W_attn,
    fp W_out, fp b_out, fp g_out, fp be_out, fp m_out, fp v_out,
    fp W_sc,  fp b_sc,  fp g_sc,  fp be_sc,  fp m_sc,  fp v_sc,
    unsigned char* __restrict__ ws)
{
    const int t = blockIdx.x * 256 + threadIdx.x;
    if (t < 2048) {                                   // W_attn frags (x log2e)
        const int n0 = t >> 8, s = (t >> 6) & 3, ln = t & 63;
        const int n = (n0 << 4) + (ln & 15);
        unsigned int v[4];
        #pragma unroll
        for (int jj = 0; jj < 4; ++jj) {
            const int k = (s << 5) + ((ln >> 4) << 3) + jj * 2;
            v[jj] = pack2(W_attn[k * CCAT + n] * LOG2E,
                          W_attn[(k + 1) * CCAT + n] * LOG2E);
        }
        *(uint4*)(ws + WS_WB + t * 16) = make_uint4(v[0], v[1], v[2], v[3]);
    } else if (t < 5120) {                            // [W_out;W_sc] BN-folded frags
        const int e = t - 2048;
        const int t8 = e / 384, rem = e % 384, s = rem >> 6, ln = rem & 63;
        const int d = (t8 << 4) + (ln & 15);
        const float so = g_out[d] * rsqrtf(v_out[d] + EPS);
        const float ss = g_sc[d]  * rsqrtf(v_sc[d]  + EPS);
        unsigned int v[4];
        #pragma unroll
        for (int jj = 0; jj < 4; ++jj) {
            float a[2];
            #pragma unroll
            for (int h = 0; h < 2; ++h) {
                const int k = (s << 5) + ((ln >> 4) << 3) + jj * 2 + h;   // 0..191
                a[h] = (k < CCAT) ? W_out[k * COUT + d] * so
                                  : W_sc[(k - CCAT) * COUT + d] * ss;
            }
            v[jj] = pack2(a[0], a[1]);
        }
        *(uint4*)(ws + WS_W3 + e * 16) = make_uint4(v[0], v[1], v[2], v[3]);
    } else if (t < 5376) {                            // W_nb BN-prescaled frags
        const int e = t - 5120;
        const int n0 = e >> 6, ln = e & 63;
        const int n = (n0 << 4) + (ln & 15);
        const float sn = g_nb[n] * rsqrtf(v_nb[n] + EPS);
        unsigned int v[4];
        #pragma unroll
        for (int jj = 0; jj < 4; ++jj) {
            float a[2];
            #pragma unroll
            for (int h = 0; h < 2; ++h) {
                const int k = ((ln >> 4) << 3) + jj * 2 + h;
                a[h] = (k < CR) ? W_nb[k * 64 + n] * sn : 0.f;
            }
            v[jj] = pack2(a[0], a[1]);
        }
        *(uint4*)(ws + WS_WNB + e * 16) = make_uint4(v[0], v[1], v[2], v[3]);
    } else if (t < 5504) {                            // bias3
        const int d = t - 5376;
        const float so = g_out[d] * rsqrtf(v_out[d] + EPS);
        const float ss = g_sc[d]  * rsqrtf(v_sc[d]  + EPS);
        ((float*)(ws + WS_B3))[d] =
              (b_out[d] - m_out[d]) * so + be_out[d]
            + (b_sc[d]  - m_sc[d])  * ss + be_sc[d];
    } else if (t < 5568) {                            // nb bias
        const int d = t - 5504;
        const float sn = g_nb[d] * rsqrtf(v_nb[d] + EPS);
        ((float*)(ws + WS_BNB))[d] = (b_nb[d] - m_nb[d]) * sn + be_nb[d];
    }
}

// ---------------------------------------------------------------------------
// Prep 2: bf16 feature table [NPTS][CIN] into ws+WS_FEA (8 ch per thread).
// ---------------------------------------------------------------------------
__global__ __launch_bounds__(256) void lfa_prep_fea(
    fp feature, unsigned char* __restrict__ ws)
{
    const int t = blockIdx.x * 256 + threadIdx.x;
    const size_t idx = (size_t)t * 8;
    if (idx < (size_t)NPTS * CIN) {
        const float4 f0 = *(const float4*)&feature[idx];
        const float4 f1 = *(const float4*)&feature[idx + 4];
        uint4 o;
        o.x = pack2(f0.x, f0.y); o.y = pack2(f0.z, f0.w);
        o.z = pack2(f1.x, f1.y); o.w = pack2(f1.z, f1.w);
        *(uint4*)(ws + WS_FEA + idx * 2) = o;
    }
}

// ---------------------------------------------------------------------------
// Main (fast path): ONE WAVE PER BLOCK, point-paired inner loop, raw-first
// VMEM issue order, LDS-only nb outputs, setprio on MFMA cluster, nt hints
// on all zero-L1-reuse streams. 8192 blocks x 64 thr. LDS = 15104 B.
// ---------------------------------------------------------------------------
__global__ __launch_bounds__(64, 2) void lfa_main_bf16(
    fp raw, const int* __restrict__ nidx,
    const unsigned char* __restrict__ ws, float* __restrict__ out)
{
    __shared__ __align__(16) unsigned short feaA[2][16][136];   // 8704 B
    __shared__ __align__(16) unsigned short pooledA[16][200];   // 6400 B

    const int lane = threadIdx.x;              // 0..63
    const int quad = lane >> 4;
    const int l15  = lane & 15;
    const int p0   = blockIdx.x * 16;          // block's 16 points
    const int b    = p0 >> 16;                 // batch (16-pt range never straddles)

    const unsigned short* feaT = (const unsigned short*)(ws + WS_FEA);
    const unsigned char*  wbp  = ws + WS_WB + ((size_t)lane << 4);

    // ---- hoisted: center rows for ALL 16 points -> pooledA[:,128..191] ----
    #pragma unroll
    for (int j = 0; j < 4; ++j) {
        const int e   = j * 64 + lane;         // 0..255
        const int row = e >> 4, c4 = (e & 15) * 4;
        const u32x2 cf = nt_u2(&feaT[(size_t)(p0 + row) * CIN + c4]);
        *(u32x2*)&pooledA[row][CCAT + c4] = cf;
    }

    float binb[4];
    #pragma unroll
    for (int j = 0; j < 4; ++j)
        binb[j] = ((const float*)(ws + WS_BNB))[j * 16 + l15];

    #pragma unroll 1
    for (int it = 0; it < 8; ++it) {
        const int pp0 = p0 + it * 2;

        // ---- (a) neighbor indices, both pts (oldest VMEM; int4, no shfl) ----
        const i32x4 ni40 = nt_i4(&nidx[(size_t)(pp0 + 0) * KNB + quad * 4]);
        const i32x4 ni41 = nt_i4(&nidx[(size_t)(pp0 + 1) * KNB + quad * 4]);

        // ---- (b) raw loads issued BEFORE gathers (consumed first; FIFO) ----
        f32x2 rw[2][4];
        #pragma unroll
        for (int pt = 0; pt < 2; ++pt) {
            const float* rp = raw + (size_t)(pp0 + pt) * (KNB * CR) + l15 * CR;
            if (quad == 0) {
                rw[pt][0] = nt_f2(rp + 0);
                rw[pt][1] = nt_f2(rp + 2);
                rw[pt][2] = nt_f2(rp + 4);
                rw[pt][3] = nt_f2(rp + 6);
            } else if (quad == 1) {
                rw[pt][0] = nt_f2(rp + 8);
            }
        }

        // ---- (c) gathers (younger than raw; consumed after nb-MLP) ----
        u32x2 gv[2][4];
        gv[0][0] = nt_u2(&feaT[(size_t)((b << 16) + ni40[0]) * CIN + l15 * 4]);
        gv[0][1] = nt_u2(&feaT[(size_t)((b << 16) + ni40[1]) * CIN + l15 * 4]);
        gv[0][2] = nt_u2(&feaT[(size_t)((b << 16) + ni40[2]) * CIN + l15 * 4]);
        gv[0][3] = nt_u2(&feaT[(size_t)((b << 16) + ni40[3]) * CIN + l15 * 4]);
        gv[1][0] = nt_u2(&feaT[(size_t)((b << 16) + ni41[0]) * CIN + l15 * 4]);
        gv[1][1] = nt_u2(&feaT[(size_t)((b << 16) + ni41[1]) * CIN + l15 * 4]);
        gv[1][2] = nt_u2(&feaT[(size_t)((b << 16) + ni41[2]) * CIN + l15 * 4]);
        gv[1][3] = nt_u2(&feaT[(size_t)((b << 16) + ni41[3]) * CIN + l15 * 4]);

        // ---- (d) anb pack — waits raw only (gathers keep flying) ----
        bf16x8 anb[2];
        #pragma unroll
        for (int pt = 0; pt < 2; ++pt) {
            bf16x8 a = {0, 0, 0, 0, 0, 0, 0, 0};
            if (quad == 0) {
                a[0] = (short)f2bf(rw[pt][0][0]); a[1] = (short)f2bf(rw[pt][0][1]);
                a[2] = (short)f2bf(rw[pt][1][0]); a[3] = (short)f2bf(rw[pt][1][1]);
                a[4] = (short)f2bf(rw[pt][2][0]); a[5] = (short)f2bf(rw[pt][2][1]);
                a[6] = (short)f2bf(rw[pt][3][0]); a[7] = (short)f2bf(rw[pt][3][1]);
            } else if (quad == 1) {
                a[0] = (short)f2bf(rw[pt][0][0]); a[1] = (short)f2bf(rw[pt][0][1]);
            }
            anb[pt] = a;
        }

        // ---- (e) nb-MLP: per-tile WNB frag -> two MFMAs -> feaA only ----
        #pragma unroll
        for (int n0 = 0; n0 < 4; ++n0) {
            const bf16x8 bw = *(const bf16x8*)(ws + WS_WNB + ((n0 * 64 + lane) << 4));
            f32x4 c0 = {0.f, 0.f, 0.f, 0.f};
            f32x4 c1 = {0.f, 0.f, 0.f, 0.f};
            c0 = __builtin_amdgcn_mfma_f32_16x16x32_bf16(anb[0], bw, c0, 0, 0, 0);
            c1 = __builtin_amdgcn_mfma_f32_16x16x32_bf16(anb[1], bw, c1, 0, 0, 0);
            #pragma unroll
            for (int r = 0; r < 4; ++r) {
                feaA[0][quad * 4 + r][64 + n0 * 16 + l15] = f2bf(lrelu(c0[r] + binb[n0]));
                feaA[1][quad * 4 + r][64 + n0 * 16 + l15] = f2bf(lrelu(c1[r] + binb[n0]));
            }
        }

        // ---- (f) gather writes (lane owns rows quad*4+i; wait ~0 by now) ----
        #pragma unroll
        for (int pt = 0; pt < 2; ++pt)
            #pragma unroll
            for (int i = 0; i < 4; ++i)
                *(u32x2*)&feaA[pt][quad * 4 + i][l15 * 4] = gv[pt][i];

        // ---- attn A-frags for both pts ----
        bf16x8 A[2][4];
        #pragma unroll
        for (int pt = 0; pt < 2; ++pt)
            #pragma unroll
            for (int s = 0; s < 4; ++s)
                A[pt][s] = *(const bf16x8*)&feaA[pt][l15][s * 32 + quad * 8];

        // ---- phase 2: 8 d-tiles, ONE wb set -> TWO independent MFMA chains,
        //      unified softmax numerator (all n0 read feaA) ----
        #pragma unroll
        for (int n0 = 0; n0 < 8; ++n0) {
            const bf16x8 wb0 = *(const bf16x8*)(wbp + (n0 * 4 + 0) * 1024);
            const bf16x8 wb1 = *(const bf16x8*)(wbp + (n0 * 4 + 1) * 1024);
            const bf16x8 wb2 = *(const bf16x8*)(wbp + (n0 * 4 + 2) * 1024);
            const bf16x8 wb3 = *(const bf16x8*)(wbp + (n0 * 4 + 3) * 1024);
            f32x4 c0 = {0.f, 0.f, 0.f, 0.f};
            f32x4 c1 = {0.f, 0.f, 0.f, 0.f};
            __builtin_amdgcn_s_setprio(1);
            c0 = __builtin_amdgcn_mfma_f32_16x16x32_bf16(A[0][0], wb0, c0, 0, 0, 0);
            c1 = __builtin_amdgcn_mfma_f32_16x16x32_bf16(A[1][0], wb0, c1, 0, 0, 0);
            c0 = __builtin_amdgcn_mfma_f32_16x16x32_bf16(A[0][1], wb1, c0, 0, 0, 0);
            c1 = __builtin_amdgcn_mfma_f32_16x16x32_bf16(A[1][1], wb1, c1, 0, 0, 0);
            c0 = __builtin_amdgcn_mfma_f32_16x16x32_bf16(A[0][2], wb2, c0, 0, 0, 0);
            c1 = __builtin_amdgcn_mfma_f32_16x16x32_bf16(A[1][2], wb2, c1, 0, 0, 0);
            c0 = __builtin_amdgcn_mfma_f32_16x16x32_bf16(A[0][3], wb3, c0, 0, 0, 0);
            c1 = __builtin_amdgcn_mfma_f32_16x16x32_bf16(A[1][3], wb3, c1, 0, 0, 0);
            __builtin_amdgcn_s_setprio(0);

            const float e00 = __builtin_amdgcn_exp2f(c0[0]);
            const float e01 = __builtin_amdgcn_exp2f(c0[1]);
            const float e02 = __builtin_amdgcn_exp2f(c0[2]);
            const float e03 = __builtin_amdgcn_exp2f(c0[3]);
            const float e10 = __builtin_amdgcn_exp2f(c1[0]);
            const float e11 = __builtin_amdgcn_exp2f(c1[1]);
            const float e12 = __builtin_amdgcn_exp2f(c1[2]);
            const float e13 = __builtin_amdgcn_exp2f(c1[3]);
            float den0 = e00 + e01 + e02 + e03;
            float den1 = e10 + e11 + e12 + e13;
            float num0, num1;
            num0 = e00 * bf2f(feaA[0][quad * 4 + 0][n0 * 16 + l15])
                 + e01 * bf2f(feaA[0][quad * 4 + 1][n0 * 16 + l15])
                 + e02 * bf2f(feaA[0][quad * 4 + 2][n0 * 16 + l15])
                 + e03 * bf2f(feaA[0][quad * 4 + 3][n0 * 16 + l15]);
            num1 = e10 * bf2f(feaA[1][quad * 4 + 0][n0 * 16 + l15])
                 + e11 * bf2f(feaA[1][quad * 4 + 1][n0 * 16 + l15])
                 + e12 * bf2f(feaA[1][quad * 4 + 2][n0 * 16 + l15])
                 + e13 * bf2f(feaA[1][quad * 4 + 3][n0 * 16 + l15]);
            num0 += __shfl_xor(num0, 16, 64);
            den0 += __shfl_xor(den0, 16, 64);
            num1 += __shfl_xor(num1, 16, 64);
            den1 += __shfl_xor(den1, 16, 64);
            num0 += __shfl_xor(num0, 32, 64);
            den0 += __shfl_xor(den0, 32, 64);
            num1 += __shfl_xor(num1, 32, 64);
            den1 += __shfl_xor(den1, 32, 64);
            const float pp0v = __fdividef(num0, den0);
            const float pp1v = __fdividef(num1, den1);
            if (quad == 0) {
                pooledA[it * 2 + 0][n0 * 16 + l15] = f2bf(pp0v);
                pooledA[it * 2 + 1][n0 * 16 + l15] = f2bf(pp1v);
            }
        }
    }

    // ---- fused phase 3: out = lrelu([pooled|feat] @ W3hat + bias3), M=16 ----
    bf16x8 A3[6];
    #pragma unroll
    for (int s = 0; s < 6; ++s)
        A3[s] = *(const bf16x8*)&pooledA[l15][s * 32 + quad * 8];
    #pragma unroll
    for (int t = 0; t < 8; ++t) {
        f32x4 c = {0.f, 0.f, 0.f, 0.f};
        #pragma unroll
        for (int s = 0; s < 6; ++s) {
            const bf16x8 bw = *(const bf16x8*)(ws + WS_W3 + (((t * 6 + s) * 64 + lane) << 4));
            c = __builtin_amdgcn_mfma_f32_16x16x32_bf16(A3[s], bw, c, 0, 0, 0);
        }
        const float bz = ((const float*)(ws + WS_B3))[t * 16 + l15];
        #pragma unroll
        for (int r = 0; r < 4; ++r)
            nt_stf(&out[(size_t)(p0 + quad * 4 + r) * COUT + t * 16 + l15],
                   lrelu(c[r] + bz));
    }
}

// ---------------------------------------------------------------------------
// Fallback main (exact r5 kernel, known 270 us): used if ws too small.
// ---------------------------------------------------------------------------
__global__ __launch_bounds__(256, 2) void lfa_main_f32(
    fp feature, fp raw, const int* __restrict__ nidx,
    const unsigned char* __restrict__ ws, float* __restrict__ out)
{
    __shared__ __align__(16) unsigned short feaA[4][16][136];
    __shared__ __align__(16) unsigned short pooledA[4][16][200];

    const int tid  = threadIdx.x;
    const int w    = tid >> 6;
    const int lane = tid & 63;
    const int quad = lane >> 4;
    const int l15  = lane & 15;
    const int p0   = (blockIdx.x * 4 + w) * 16;
    const int b    = p0 >> 16;

    bf16x8 WB[8][4];
    #pragma unroll
    for (int n0 = 0; n0 < 8; ++n0)
        #pragma unroll
        for (int s = 0; s < 4; ++s)
            WB[n0][s] = *(const bf16x8*)(ws + WS_WB + (((n0 * 4 + s) * 64 + lane) << 4));

    float binb[4];
    #pragma unroll
    for (int j = 0; j < 4; ++j)
        binb[j] = ((const float*)(ws + WS_BNB))[j * 16 + l15];

    #pragma unroll 1
    for (int it = 0; it < 8; ++it) {
        const int pp0 = p0 + it * 2;

        int idxv = 0;
        if (lane < 32) idxv = nidx[pp0 * KNB + lane];

        if (lane < 32) {
            const int pt = lane >> 4, c4 = l15 * 4;
            const float4 cf = *(const float4*)&feature[(size_t)(pp0 + pt) * CIN + c4];
            uint2 pk; pk.x = pack2(cf.x, cf.y); pk.y = pack2(cf.z, cf.w);
            *(uint2*)&pooledA[w][it * 2 + pt][CCAT + c4] = pk;
        }

        #pragma unroll
        for (int pt = 0; pt < 2; ++pt) {
            const int p = pp0 + pt;

            float4 gv[4];
            #pragma unroll
            for (int i = 0; i < 4; ++i) {
                const int ni = __shfl(idxv, pt * 16 + i * 4 + quad, 64);
                gv[i] = *(const float4*)&feature[(size_t)((b << 16) + ni) * CIN + l15 * 4];
            }

            bf16x8 anb = {0, 0, 0, 0, 0, 0, 0, 0};
            {
                const float* rp = raw + (size_t)p * (KNB * CR) + l15 * CR;
                if (quad == 0) {
                    const float2 r0 = *(const float2*)(rp + 0);
                    const float2 r1 = *(const float2*)(rp + 2);
                    const float2 r2 = *(const float2*)(rp + 4);
                    const float2 r3 = *(const float2*)(rp + 6);
                    anb[0] = (short)f2bf(r0.x); anb[1] = (short)f2bf(r0.y);
                    anb[2] = (short)f2bf(r1.x); anb[3] = (short)f2bf(r1.y);
                    anb[4] = (short)f2bf(r2.x); anb[5] = (short)f2bf(r2.y);
                    anb[6] = (short)f2bf(r3.x); anb[7] = (short)f2bf(r3.y);
                } else if (quad == 1) {
                    const float2 r4 = *(const float2*)(rp + 8);
                    anb[0] = (short)f2bf(r4.x); anb[1] = (short)f2bf(r4.y);
                }
            }

            float nbC[4][4];
            #pragma unroll
            for (int n0 = 0; n0 < 4; ++n0) {
                const bf16x8 bw = *(const bf16x8*)(ws + WS_WNB + ((n0 * 64 + lane) << 4));
                f32x4 c = {0.f, 0.f, 0.f, 0.f};
                c = __builtin_amdgcn_mfma_f32_16x16x32_bf16(anb, bw, c, 0, 0, 0);
                #pragma unroll
                for (int r = 0; r < 4; ++r) {
                    const float x = lrelu(c[r] + binb[n0]);
                    nbC[n0][r] = x;
                    feaA[w][quad * 4 + r][64 + n0 * 16 + l15] = f2bf(x);
                }
            }

            #pragma unroll
            for (int i = 0; i < 4; ++i) {
                uint2 pk; pk.x = pack2(gv[i].x, gv[i].y); pk.y = pack2(gv[i].z, gv[i].w);
                *(uint2*)&feaA[w][i * 4 + quad][l15 * 4] = pk;
            }

            bf16x8 A[4];
            #pragma unroll
            for (int s = 0; s < 4; ++s)
                A[s] = *(const bf16x8*)&feaA[w][l15][s * 32 + quad * 8];

            #pragma unroll
            for (int n0 = 0; n0 < 8; ++n0) {
                f32x4 c = {0.f, 0.f, 0.f, 0.f};
                #pragma unroll
                for (int s = 0; s < 4; ++s)
                    c = __builtin_amdgcn_mfma_f32_16x16x32_bf16(A[s], WB[n0][s], c, 0, 0, 0);
                const float e0 = __builtin_amdgcn_exp2f(c[0]);
                const float e1 = __builtin_amdgcn_exp2f(c[1]);
                const float e2 = __builtin_amdgcn_exp2f(c[2]);
                const float e3 = __builtin_amdgcn_exp2f(c[3]);
                float den = e0 + e1 + e2 + e3;
                float num;
                if (n0 < 4) {
                    num = e0 * bf2f(feaA[w][quad * 4 + 0][n0 * 16 + l15])
                        + e1 * bf2f(feaA[w][quad * 4 + 1][n0 * 16 + l15])
                        + e2 * bf2f(feaA[w][quad * 4 + 2][n0 * 16 + l15])
                        + e3 * bf2f(feaA[w][quad * 4 + 3][n0 * 16 + l15]);
                } else {
                    num = e0 * nbC[n0 - 4][0] + e1 * nbC[n0 - 4][1]
                        + e2 * nbC[n0 - 4][2] + e3 * nbC[n0 - 4][3];
                }
                num += __shfl_xor(num, 16, 64);
                den += __shfl_xor(den, 16, 64);
                num += __shfl_xor(num, 32, 64);
                den += __shfl_xor(den, 32, 64);
                const float pp = __fdividef(num, den);
                if (quad == 0)
                    pooledA[w][it * 2 + pt][n0 * 16 + l15] = f2bf(pp);
            }
        }
    }

    bf16x8 A3[6];
    #pragma unroll
    for (int s = 0; s < 6; ++s)
        A3[s] = *(const bf16x8*)&pooledA[w][l15][s * 32 + quad * 8];
    #pragma unroll
    for (int t = 0; t < 8; ++t) {
        f32x4 c = {0.f, 0.f, 0.f, 0.f};
        #pragma unroll
        for (int s = 0; s < 6; ++s) {
            const bf16x8 bw = *(const bf16x8*)(ws + WS_W3 + (((t * 6 + s) * 64 + lane) << 4));
            c = __builtin_amdgcn_mfma_f32_16x16x32_bf16(A3[s], bw, c, 0, 0, 0);
        }
        const float bz = ((const float*)(ws + WS_B3))[t * 16 + l15];
        #pragma unroll
        for (int r = 0; r < 4; ++r)
            out[(size_t)(p0 + quad * 4 + r) * COUT + t * 16 + l15] = lrelu(c[r] + bz);
    }
}

extern "C" void kernel_launch(void* const* d_in, const int* in_sizes, int n_in,
                              void* d_out, int out_size, void* d_ws, size_t ws_size,
                              hipStream_t stream)
{
    fp feature = (fp)d_in[1];
    fp raw     = (fp)d_in[2];
    const int* nidx = (const int*)d_in[3];
    fp W_nb = (fp)d_in[4],  b_nb = (fp)d_in[5],  g_nb = (fp)d_in[6];
    fp be_nb = (fp)d_in[7], m_nb = (fp)d_in[8],  v_nb = (fp)d_in[9];
    fp W_attn = (fp)d_in[10];
    fp W_out = (fp)d_in[11], b_out = (fp)d_in[12], g_out = (fp)d_in[13];
    fp be_out = (fp)d_in[14], m_out = (fp)d_in[15], v_out = (fp)d_in[16];
    fp W_sc = (fp)d_in[17], b_sc = (fp)d_in[18], g_sc = (fp)d_in[19];
    fp be_sc = (fp)d_in[20], m_sc = (fp)d_in[21], v_sc = (fp)d_in[22];

    hipLaunchKernelGGL(lfa_prep, dim3(22), dim3(256), 0, stream,
                       W_nb, b_nb, g_nb, be_nb, m_nb, v_nb,
                       W_attn,
                       W_out, b_out, g_out, be_out, m_out, v_out,
                       W_sc, b_sc, g_sc, be_sc, m_sc, v_sc,
                       (unsigned char*)d_ws);

    const size_t need = (size_t)WS_FEA + (size_t)NPTS * CIN * 2;
    if (ws_size >= need) {
        hipLaunchKernelGGL(lfa_prep_fea, dim3(4096), dim3(256), 0, stream,
                           feature, (unsigned char*)d_ws);
        hipLaunchKernelGGL(lfa_main_bf16, dim3(8192), dim3(64), 0, stream,
                           raw, nidx, (const unsigned char*)d_ws, (float*)d_out);
    } else {
        hipLaunchKernelGGL(lfa_main_f32, dim3(2048), dim3(256), 0, stream,
                           feature, raw, nidx,
                           (const unsigned char*)d_ws, (float*)d_out);
    }
}

// Round 16
// 362.721 us; speedup vs baseline: 1.0352x; 1.0352x over previous
//
#include <hip/hip_runtime.h>

// LocalFeatureAggregation — round 19 (FINAL): revert r18's nt hints to the
// verified best kernel (r16: 205us main / 364us total).
//  * r18 verdict: nt null on time (206 vs 205), negative on traffic (WRITE
//    65.5->92MB partial-line writebacks, FETCH 147->159MB) -> WB table was
//    already L1-resident; L1 pollution is NOT the stall. Full revert.
//  * Plateau evidence: occupancy pinned ~22% across 5 resource configs;
//    VGPR-128 law (129+ halves residency); all serial chains cut (no-shfl
//    idx, raw-first FIFO, nbC->LDS); staging/prefetch arcs measured worse.
//    Residual ~34% issue-idle = per-wave latency at ~1.75 waves/SIMD.
//  * Session: 283 -> 205 us main (432 -> 364 total).
// Requires ws_size >= 16864256 for the fast path (>= 86784 for fallback).

#define KNB   16
#define CR    10
#define CIN   64
#define CCAT  128
#define COUT  128
#define NPTS  131072
#define EPS   1e-5f
#define LOG2E 1.4426950408889634f

// d_ws layout (bytes)
#define WS_WB   0        // W_attn B-frags (pre-scaled by log2e): 2048 * 16 B = 32768
#define WS_W3   32768    // [W_out;W_sc] BN-folded B-frags: 3072 * 16 B = 49152
#define WS_WNB  81920    // W_nb BN-folded B-frags (K padded to 32): 256 * 16 B = 4096
#define WS_B3   86016    // bias3[128] fp32
#define WS_BNB  86528    // binb[64] fp32   -> 86784
#define WS_FEA  87040    // bf16 feature table [NPTS][CIN]: 16777216 B -> total 16864256

typedef const float* fp;
typedef short bf16x8 __attribute__((ext_vector_type(8)));
typedef float f32x4  __attribute__((ext_vector_type(4)));
typedef __bf16 bf16x2 __attribute__((ext_vector_type(2)));

__device__ __forceinline__ unsigned short f2bf(float x) {
    return __builtin_bit_cast(unsigned short, (__bf16)x);     // HW RNE cvt
}
__device__ __forceinline__ unsigned int pack2(float a, float b) {
    bf16x2 v; v.x = (__bf16)a; v.y = (__bf16)b;               // v_cvt_pk_bf16_f32
    return __builtin_bit_cast(unsigned int, v);
}
__device__ __forceinline__ float bf2f(unsigned short h) {
    return __uint_as_float(((unsigned int)h) << 16);
}
__device__ __forceinline__ float lrelu(float x) { return fmaxf(x, 0.2f * x); }

// ---------------------------------------------------------------------------
// Prep: build all weight-fragment tables in d_ws.
// ---------------------------------------------------------------------------
__global__ __launch_bounds__(256) void lfa_prep(
    fp W_nb, fp b_nb, fp g_nb, fp be_nb, fp m_nb, fp v_nb,
    fp W_attn,
    fp W_out, fp b_out, fp g_out, fp be_out, fp m_out, fp v_out,
    fp W_sc,  fp b_sc,  fp g_sc,  fp be_sc,  fp m_sc,  fp v_sc,
    unsigned char* __restrict__ ws)
{
    const int t = blockIdx.x * 256 + threadIdx.x;
    if (t < 2048) {                                   // W_attn frags (x log2e)
        const int n0 = t >> 8, s = (t >> 6) & 3, ln = t & 63;
        const int n = (n0 << 4) + (ln & 15);
        unsigned int v[4];
        #pragma unroll
        for (int jj = 0; jj < 4; ++jj) {
            const int k = (s << 5) + ((ln >> 4) << 3) + jj * 2;
            v[jj] = pack2(W_attn[k * CCAT + n] * LOG2E,
                          W_attn[(k + 1) * CCAT + n] * LOG2E);
        }
        *(uint4*)(ws + WS_WB + t * 16) = make_uint4(v[0], v[1], v[2], v[3]);
    } else if (t < 5120) {                            // [W_out;W_sc] BN-folded frags
        const int e = t - 2048;
        const int t8 = e / 384, rem = e % 384, s = rem >> 6, ln = rem & 63;
        const int d = (t8 << 4) + (ln & 15);
        const float so = g_out[d] * rsqrtf(v_out[d] + EPS);
        const float ss = g_sc[d]  * rsqrtf(v_sc[d]  + EPS);
        unsigned int v[4];
        #pragma unroll
        for (int jj = 0; jj < 4; ++jj) {
            float a[2];
            #pragma unroll
            for (int h = 0; h < 2; ++h) {
                const int k = (s << 5) + ((ln >> 4) << 3) + jj * 2 + h;   // 0..191
                a[h] = (k < CCAT) ? W_out[k * COUT + d] * so
                                  : W_sc[(k - CCAT) * COUT + d] * ss;
            }
            v[jj] = pack2(a[0], a[1]);
        }
        *(uint4*)(ws + WS_W3 + e * 16) = make_uint4(v[0], v[1], v[2], v[3]);
    } else if (t < 5376) {                            // W_nb BN-prescaled frags
        const int e = t - 5120;
        const int n0 = e >> 6, ln = e & 63;
        const int n = (n0 << 4) + (ln & 15);
        const float sn = g_nb[n] * rsqrtf(v_nb[n] + EPS);
        unsigned int v[4];
        #pragma unroll
        for (int jj = 0; jj < 4; ++jj) {
            float a[2];
            #pragma unroll
            for (int h = 0; h < 2; ++h) {
                const int k = ((ln >> 4) << 3) + jj * 2 + h;
                a[h] = (k < CR) ? W_nb[k * 64 + n] * sn : 0.f;
            }
            v[jj] = pack2(a[0], a[1]);
        }
        *(uint4*)(ws + WS_WNB + e * 16) = make_uint4(v[0], v[1], v[2], v[3]);
    } else if (t < 5504) {                            // bias3
        const int d = t - 5376;
        const float so = g_out[d] * rsqrtf(v_out[d] + EPS);
        const float ss = g_sc[d]  * rsqrtf(v_sc[d]  + EPS);
        ((float*)(ws + WS_B3))[d] =
              (b_out[d] - m_out[d]) * so + be_out[d]
            + (b_sc[d]  - m_sc[d])  * ss + be_sc[d];
    } else if (t < 5568) {                            // nb bias
        const int d = t - 5504;
        const float sn = g_nb[d] * rsqrtf(v_nb[d] + EPS);
        ((float*)(ws + WS_BNB))[d] = (b_nb[d] - m_nb[d]) * sn + be_nb[d];
    }
}

// ---------------------------------------------------------------------------
// Prep 2: bf16 feature table [NPTS][CIN] into ws+WS_FEA (8 ch per thread).
// ---------------------------------------------------------------------------
__global__ __launch_bounds__(256) void lfa_prep_fea(
    fp feature, unsigned char* __restrict__ ws)
{
    const int t = blockIdx.x * 256 + threadIdx.x;
    const size_t idx = (size_t)t * 8;
    if (idx < (size_t)NPTS * CIN) {
        const float4 f0 = *(const float4*)&feature[idx];
        const float4 f1 = *(const float4*)&feature[idx + 4];
        uint4 o;
        o.x = pack2(f0.x, f0.y); o.y = pack2(f0.z, f0.w);
        o.z = pack2(f1.x, f1.y); o.w = pack2(f1.z, f1.w);
        *(uint4*)(ws + WS_FEA + idx * 2) = o;
    }
}

// ---------------------------------------------------------------------------
// Main (fast path): ONE WAVE PER BLOCK, point-paired inner loop, raw-first
// VMEM issue order, LDS-only nb outputs, setprio on MFMA cluster.
// 8192 blocks x 64 thr, 16 pts/block. LDS = 15104 B. VGPR 120.
// ---------------------------------------------------------------------------
__global__ __launch_bounds__(64, 2) void lfa_main_bf16(
    fp raw, const int* __restrict__ nidx,
    const unsigned char* __restrict__ ws, float* __restrict__ out)
{
    __shared__ __align__(16) unsigned short feaA[2][16][136];   // 8704 B
    __shared__ __align__(16) unsigned short pooledA[16][200];   // 6400 B

    const int lane = threadIdx.x;              // 0..63
    const int quad = lane >> 4;
    const int l15  = lane & 15;
    const int p0   = blockIdx.x * 16;          // block's 16 points
    const int b    = p0 >> 16;                 // batch (16-pt range never straddles)

    const unsigned short* feaT = (const unsigned short*)(ws + WS_FEA);
    const unsigned char*  wbp  = ws + WS_WB + ((size_t)lane << 4);

    // ---- hoisted: center rows for ALL 16 points -> pooledA[:,128..191] ----
    #pragma unroll
    for (int j = 0; j < 4; ++j) {
        const int e   = j * 64 + lane;         // 0..255
        const int row = e >> 4, c4 = (e & 15) * 4;
        const uint2 cf = *(const uint2*)&feaT[(size_t)(p0 + row) * CIN + c4];
        *(uint2*)&pooledA[row][CCAT + c4] = cf;
    }

    float binb[4];
    #pragma unroll
    for (int j = 0; j < 4; ++j)
        binb[j] = ((const float*)(ws + WS_BNB))[j * 16 + l15];

    #pragma unroll 1
    for (int it = 0; it < 8; ++it) {
        const int pp0 = p0 + it * 2;

        // ---- (a) neighbor indices, both pts (oldest VMEM; int4, no shfl) ----
        const int4 ni40 = *(const int4*)&nidx[(size_t)(pp0 + 0) * KNB + quad * 4];
        const int4 ni41 = *(const int4*)&nidx[(size_t)(pp0 + 1) * KNB + quad * 4];

        // ---- (b) raw loads issued BEFORE gathers (consumed first; FIFO) ----
        float2 rw[2][4];
        #pragma unroll
        for (int pt = 0; pt < 2; ++pt) {
            const float* rp = raw + (size_t)(pp0 + pt) * (KNB * CR) + l15 * CR;
            if (quad == 0) {
                rw[pt][0] = *(const float2*)(rp + 0);
                rw[pt][1] = *(const float2*)(rp + 2);
                rw[pt][2] = *(const float2*)(rp + 4);
                rw[pt][3] = *(const float2*)(rp + 6);
            } else if (quad == 1) {
                rw[pt][0] = *(const float2*)(rp + 8);
            }
        }

        // ---- (c) gathers (younger than raw; consumed after nb-MLP) ----
        uint2 gv[2][4];
        gv[0][0] = *(const uint2*)&feaT[(size_t)((b << 16) + ni40.x) * CIN + l15 * 4];
        gv[0][1] = *(const uint2*)&feaT[(size_t)((b << 16) + ni40.y) * CIN + l15 * 4];
        gv[0][2] = *(const uint2*)&feaT[(size_t)((b << 16) + ni40.z) * CIN + l15 * 4];
        gv[0][3] = *(const uint2*)&feaT[(size_t)((b << 16) + ni40.w) * CIN + l15 * 4];
        gv[1][0] = *(const uint2*)&feaT[(size_t)((b << 16) + ni41.x) * CIN + l15 * 4];
        gv[1][1] = *(const uint2*)&feaT[(size_t)((b << 16) + ni41.y) * CIN + l15 * 4];
        gv[1][2] = *(const uint2*)&feaT[(size_t)((b << 16) + ni41.z) * CIN + l15 * 4];
        gv[1][3] = *(const uint2*)&feaT[(size_t)((b << 16) + ni41.w) * CIN + l15 * 4];

        // ---- (d) anb pack — waits raw only (gathers keep flying) ----
        bf16x8 anb[2];
        #pragma unroll
        for (int pt = 0; pt < 2; ++pt) {
            bf16x8 a = {0, 0, 0, 0, 0, 0, 0, 0};
            if (quad == 0) {
                a[0] = (short)f2bf(rw[pt][0].x); a[1] = (short)f2bf(rw[pt][0].y);
                a[2] = (short)f2bf(rw[pt][1].x); a[3] = (short)f2bf(rw[pt][1].y);
                a[4] = (short)f2bf(rw[pt][2].x); a[5] = (short)f2bf(rw[pt][2].y);
                a[6] = (short)f2bf(rw[pt][3].x); a[7] = (short)f2bf(rw[pt][3].y);
            } else if (quad == 1) {
                a[0] = (short)f2bf(rw[pt][0].x); a[1] = (short)f2bf(rw[pt][0].y);
            }
            anb[pt] = a;
        }

        // ---- (e) nb-MLP: per-tile WNB frag -> two MFMAs -> feaA only ----
        #pragma unroll
        for (int n0 = 0; n0 < 4; ++n0) {
            const bf16x8 bw = *(const bf16x8*)(ws + WS_WNB + ((n0 * 64 + lane) << 4));
            f32x4 c0 = {0.f, 0.f, 0.f, 0.f};
            f32x4 c1 = {0.f, 0.f, 0.f, 0.f};
            c0 = __builtin_amdgcn_mfma_f32_16x16x32_bf16(anb[0], bw, c0, 0, 0, 0);
            c1 = __builtin_amdgcn_mfma_f32_16x16x32_bf16(anb[1], bw, c1, 0, 0, 0);
            #pragma unroll
            for (int r = 0; r < 4; ++r) {
                feaA[0][quad * 4 + r][64 + n0 * 16 + l15] = f2bf(lrelu(c0[r] + binb[n0]));
                feaA[1][quad * 4 + r][64 + n0 * 16 + l15] = f2bf(lrelu(c1[r] + binb[n0]));
            }
        }

        // ---- (f) gather writes (lane owns rows quad*4+i; wait ~0 by now) ----
        #pragma unroll
        for (int pt = 0; pt < 2; ++pt)
            #pragma unroll
            for (int i = 0; i < 4; ++i)
                *(uint2*)&feaA[pt][quad * 4 + i][l15 * 4] = gv[pt][i];

        // ---- attn A-frags for both pts ----
        bf16x8 A[2][4];
        #pragma unroll
        for (int pt = 0; pt < 2; ++pt)
            #pragma unroll
            for (int s = 0; s < 4; ++s)
                A[pt][s] = *(const bf16x8*)&feaA[pt][l15][s * 32 + quad * 8];

        // ---- phase 2: 8 d-tiles, ONE wb set -> TWO independent MFMA chains,
        //      unified softmax numerator (all n0 read feaA) ----
        #pragma unroll
        for (int n0 = 0; n0 < 8; ++n0) {
            const bf16x8 wb0 = *(const bf16x8*)(wbp + (n0 * 4 + 0) * 1024);
            const bf16x8 wb1 = *(const bf16x8*)(wbp + (n0 * 4 + 1) * 1024);
            const bf16x8 wb2 = *(const bf16x8*)(wbp + (n0 * 4 + 2) * 1024);
            const bf16x8 wb3 = *(const bf16x8*)(wbp + (n0 * 4 + 3) * 1024);
            f32x4 c0 = {0.f, 0.f, 0.f, 0.f};
            f32x4 c1 = {0.f, 0.f, 0.f, 0.f};
            __builtin_amdgcn_s_setprio(1);
            c0 = __builtin_amdgcn_mfma_f32_16x16x32_bf16(A[0][0], wb0, c0, 0, 0, 0);
            c1 = __builtin_amdgcn_mfma_f32_16x16x32_bf16(A[1][0], wb0, c1, 0, 0, 0);
            c0 = __builtin_amdgcn_mfma_f32_16x16x32_bf16(A[0][1], wb1, c0, 0, 0, 0);
            c1 = __builtin_amdgcn_mfma_f32_16x16x32_bf16(A[1][1], wb1, c1, 0, 0, 0);
            c0 = __builtin_amdgcn_mfma_f32_16x16x32_bf16(A[0][2], wb2, c0, 0, 0, 0);
            c1 = __builtin_amdgcn_mfma_f32_16x16x32_bf16(A[1][2], wb2, c1, 0, 0, 0);
            c0 = __builtin_amdgcn_mfma_f32_16x16x32_bf16(A[0][3], wb3, c0, 0, 0, 0);
            c1 = __builtin_amdgcn_mfma_f32_16x16x32_bf16(A[1][3], wb3, c1, 0, 0, 0);
            __builtin_amdgcn_s_setprio(0);

            const float e00 = __builtin_amdgcn_exp2f(c0[0]);
            const float e01 = __builtin_amdgcn_exp2f(c0[1]);
            const float e02 = __builtin_amdgcn_exp2f(c0[2]);
            const float e03 = __builtin_amdgcn_exp2f(c0[3]);
            const float e10 = __builtin_amdgcn_exp2f(c1[0]);
            const float e11 = __builtin_amdgcn_exp2f(c1[1]);
            const float e12 = __builtin_amdgcn_exp2f(c1[2]);
            const float e13 = __builtin_amdgcn_exp2f(c1[3]);
            float den0 = e00 + e01 + e02 + e03;
            float den1 = e10 + e11 + e12 + e13;
            float num0, num1;
            num0 = e00 * bf2f(feaA[0][quad * 4 + 0][n0 * 16 + l15])
                 + e01 * bf2f(feaA[0][quad * 4 + 1][n0 * 16 + l15])
                 + e02 * bf2f(feaA[0][quad * 4 + 2][n0 * 16 + l15])
                 + e03 * bf2f(feaA[0][quad * 4 + 3][n0 * 16 + l15]);
            num1 = e10 * bf2f(feaA[1][quad * 4 + 0][n0 * 16 + l15])
                 + e11 * bf2f(feaA[1][quad * 4 + 1][n0 * 16 + l15])
                 + e12 * bf2f(feaA[1][quad * 4 + 2][n0 * 16 + l15])
                 + e13 * bf2f(feaA[1][quad * 4 + 3][n0 * 16 + l15]);
            num0 += __shfl_xor(num0, 16, 64);
            den0 += __shfl_xor(den0, 16, 64);
            num1 += __shfl_xor(num1, 16, 64);
            den1 += __shfl_xor(den1, 16, 64);
            num0 += __shfl_xor(num0, 32, 64);
            den0 += __shfl_xor(den0, 32, 64);
            num1 += __shfl_xor(num1, 32, 64);
            den1 += __shfl_xor(den1, 32, 64);
            const float pp0v = __fdividef(num0, den0);
            const float pp1v = __fdividef(num1, den1);
            if (quad == 0) {
                pooledA[it * 2 + 0][n0 * 16 + l15] = f2bf(pp0v);
                pooledA[it * 2 + 1][n0 * 16 + l15] = f2bf(pp1v);
            }
        }
    }

    // ---- fused phase 3: out = lrelu([pooled|feat] @ W3hat + bias3), M=16 ----
    bf16x8 A3[6];
    #pragma unroll
    for (int s = 0; s < 6; ++s)
        A3[s] = *(const bf16x8*)&pooledA[l15][s * 32 + quad * 8];
    #pragma unroll
    for (int t = 0; t < 8; ++t) {
        f32x4 c = {0.f, 0.f, 0.f, 0.f};
        #pragma unroll
        for (int s = 0; s < 6; ++s) {
            const bf16x8 bw = *(const bf16x8*)(ws + WS_W3 + (((t * 6 + s) * 64 + lane) << 4));
            c = __builtin_amdgcn_mfma_f32_16x16x32_bf16(A3[s], bw, c, 0, 0, 0);
        }
        const float bz = ((const float*)(ws + WS_B3))[t * 16 + l15];
        #pragma unroll
        for (int r = 0; r < 4; ++r)
            out[(size_t)(p0 + quad * 4 + r) * COUT + t * 16 + l15] = lrelu(c[r] + bz);
    }
}

// ---------------------------------------------------------------------------
// Fallback main (exact r5 kernel, known 270 us): used if ws too small.
// ---------------------------------------------------------------------------
__global__ __launch_bounds__(256, 2) void lfa_main_f32(
    fp feature, fp raw, const int* __restrict__ nidx,
    const unsigned char* __restrict__ ws, float* __restrict__ out)
{
    __shared__ __align__(16) unsigned short feaA[4][16][136];
    __shared__ __align__(16) unsigned short pooledA[4][16][200];

    const int tid  = threadIdx.x;
    const int w    = tid >> 6;
    const int lane = tid & 63;
    const int quad = lane >> 4;
    const int l15  = lane & 15;
    const int p0   = (blockIdx.x * 4 + w) * 16;
    const int b    = p0 >> 16;

    bf16x8 WB[8][4];
    #pragma unroll
    for (int n0 = 0; n0 < 8; ++n0)
        #pragma unroll
        for (int s = 0; s < 4; ++s)
            WB[n0][s] = *(const bf16x8*)(ws + WS_WB + (((n0 * 4 + s) * 64 + lane) << 4));

    float binb[4];
    #pragma unroll
    for (int j = 0; j < 4; ++j)
        binb[j] = ((const float*)(ws + WS_BNB))[j * 16 + l15];

    #pragma unroll 1
    for (int it = 0; it < 8; ++it) {
        const int pp0 = p0 + it * 2;

        int idxv = 0;
        if (lane < 32) idxv = nidx[pp0 * KNB + lane];

        if (lane < 32) {
            const int pt = lane >> 4, c4 = l15 * 4;
            const float4 cf = *(const float4*)&feature[(size_t)(pp0 + pt) * CIN + c4];
            uint2 pk; pk.x = pack2(cf.x, cf.y); pk.y = pack2(cf.z, cf.w);
            *(uint2*)&pooledA[w][it * 2 + pt][CCAT + c4] = pk;
        }

        #pragma unroll
        for (int pt = 0; pt < 2; ++pt) {
            const int p = pp0 + pt;

            float4 gv[4];
            #pragma unroll
            for (int i = 0; i < 4; ++i) {
                const int ni = __shfl(idxv, pt * 16 + i * 4 + quad, 64);
                gv[i] = *(const float4*)&feature[(size_t)((b << 16) + ni) * CIN + l15 * 4];
            }

            bf16x8 anb = {0, 0, 0, 0, 0, 0, 0, 0};
            {
                const float* rp = raw + (size_t)p * (KNB * CR) + l15 * CR;
                if (quad == 0) {
                    const float2 r0 = *(const float2*)(rp + 0);
                    const float2 r1 = *(const float2*)(rp + 2);
                    const float2 r2 = *(const float2*)(rp + 4);
                    const float2 r3 = *(const float2*)(rp + 6);
                    anb[0] = (short)f2bf(r0.x); anb[1] = (short)f2bf(r0.y);
                    anb[2] = (short)f2bf(r1.x); anb[3] = (short)f2bf(r1.y);
                    anb[4] = (short)f2bf(r2.x); anb[5] = (short)f2bf(r2.y);
                    anb[6] = (short)f2bf(r3.x); anb[7] = (short)f2bf(r3.y);
                } else if (quad == 1) {
                    const float2 r4 = *(const float2*)(rp + 8);
                    anb[0] = (short)f2bf(r4.x); anb[1] = (short)f2bf(r4.y);
                }
            }

            float nbC[4][4];
            #pragma unroll
            for (int n0 = 0; n0 < 4; ++n0) {
                const bf16x8 bw = *(const bf16x8*)(ws + WS_WNB + ((n0 * 64 + lane) << 4));
                f32x4 c = {0.f, 0.f, 0.f, 0.f};
                c = __builtin_amdgcn_mfma_f32_16x16x32_bf16(anb, bw, c, 0, 0, 0);
                #pragma unroll
                for (int r = 0; r < 4; ++r) {
                    const float x = lrelu(c[r] + binb[n0]);
                    nbC[n0][r] = x;
                    feaA[w][quad * 4 + r][64 + n0 * 16 + l15] = f2bf(x);
                }
            }

            #pragma unroll
            for (int i = 0; i < 4; ++i) {
                uint2 pk; pk.x = pack2(gv[i].x, gv[i].y); pk.y = pack2(gv[i].z, gv[i].w);
                *(uint2*)&feaA[w][i * 4 + quad][l15 * 4] = pk;
            }

            bf16x8 A[4];
            #pragma unroll
            for (int s = 0; s < 4; ++s)
                A[s] = *(const bf16x8*)&feaA[w][l15][s * 32 + quad * 8];

            #pragma unroll
            for (int n0 = 0; n0 < 8; ++n0) {
                f32x4 c = {0.f, 0.f, 0.f, 0.f};
                #pragma unroll
                for (int s = 0; s < 4; ++s)
                    c = __builtin_amdgcn_mfma_f32_16x16x32_bf16(A[s], WB[n0][s], c, 0, 0, 0);
                const float e0 = __builtin_amdgcn_exp2f(c[0]);
                const float e1 = __builtin_amdgcn_exp2f(c[1]);
                const float e2 = __builtin_amdgcn_exp2f(c[2]);
                const float e3 = __builtin_amdgcn_exp2f(c[3]);
                float den = e0 + e1 + e2 + e3;
                float num;
                if (n0 < 4) {
                    num = e0 * bf2f(feaA[w][quad * 4 + 0][n0 * 16 + l15])
                        + e1 * bf2f(feaA[w][quad * 4 + 1][n0 * 16 + l15])
                        + e2 * bf2f(feaA[w][quad * 4 + 2][n0 * 16 + l15])
                        + e3 * bf2f(feaA[w][quad * 4 + 3][n0 * 16 + l15]);
                } else {
                    num = e0 * nbC[n0 - 4][0] + e1 * nbC[n0 - 4][1]
                        + e2 * nbC[n0 - 4][2] + e3 * nbC[n0 - 4][3];
                }
                num += __shfl_xor(num, 16, 64);
                den += __shfl_xor(den, 16, 64);
                num += __shfl_xor(num, 32, 64);
                den += __shfl_xor(den, 32, 64);
                const float pp = __fdividef(num, den);
                if (quad == 0)
                    pooledA[w][it * 2 + pt][n0 * 16 + l15] = f2bf(pp);
            }
        }
    }

    bf16x8 A3[6];
    #pragma unroll
    for (int s = 0; s < 6; ++s)
        A3[s] = *(const bf16x8*)&pooledA[w][l15][s * 32 + quad * 8];
    #pragma unroll
    for (int t = 0; t < 8; ++t) {
        f32x4 c = {0.f, 0.f, 0.f, 0.f};
        #pragma unroll
        for (int s = 0; s < 6; ++s) {
            const bf16x8 bw = *(const bf16x8*)(ws + WS_W3 + (((t * 6 + s) * 64 + lane) << 4));
            c = __builtin_amdgcn_mfma_f32_16x16x32_bf16(A3[s], bw, c, 0, 0, 0);
        }
        const float bz = ((const float*)(ws + WS_B3))[t * 16 + l15];
        #pragma unroll
        for (int r = 0; r < 4; ++r)
            out[(size_t)(p0 + quad * 4 + r) * COUT + t * 16 + l15] = lrelu(c[r] + bz);
    }
}

extern "C" void kernel_launch(void* const* d_in, const int* in_sizes, int n_in,
                              void* d_out, int out_size, void* d_ws, size_t ws_size,
                              hipStream_t stream)
{
    fp feature = (fp)d_in[1];
    fp raw     = (fp)d_in[2];
    const int* nidx = (const int*)d_in[3];
    fp W_nb = (fp)d_in[4],  b_nb = (fp)d_in[5],  g_nb = (fp)d_in[6];
    fp be_nb = (fp)d_in[7], m_nb = (fp)d_in[8],  v_nb = (fp)d_in[9];
    fp W_attn = (fp)d_in[10];
    fp W_out = (fp)d_in[11], b_out = (fp)d_in[12], g_out = (fp)d_in[13];
    fp be_out = (fp)d_in[14], m_out = (fp)d_in[15], v_out = (fp)d_in[16];
    fp W_sc = (fp)d_in[17], b_sc = (fp)d_in[18], g_sc = (fp)d_in[19];
    fp be_sc = (fp)d_in[20], m_sc = (fp)d_in[21], v_sc = (fp)d_in[22];

    hipLaunchKernelGGL(lfa_prep, dim3(22), dim3(256), 0, stream,
                       W_nb, b_nb, g_nb, be_nb, m_nb, v_nb,
                       W_attn,
                       W_out, b_out, g_out, be_out, m_out, v_out,
                       W_sc, b_sc, g_sc, be_sc, m_sc, v_sc,
                       (unsigned char*)d_ws);

    const size_t need = (size_t)WS_FEA + (size_t)NPTS * CIN * 2;
    if (ws_size >= need) {
        hipLaunchKernelGGL(lfa_prep_fea, dim3(4096), dim3(256), 0, stream,
                           feature, (unsigned char*)d_ws);
        hipLaunchKernelGGL(lfa_main_bf16, dim3(8192), dim3(64), 0, stream,
                           raw, nidx, (const unsigned char*)d_ws, (float*)d_out);
    } else {
        hipLaunchKernelGGL(lfa_main_f32, dim3(2048), dim3(256), 0, stream,
                           feature, raw, nidx,
                           (const unsigned char*)d_ws, (float*)d_out);
    }
}